// Round 16
// baseline (87.794 us; speedup 1.0000x reference)
//
#include <hip/hip_runtime.h>
#include <hip/hip_bf16.h>
#include <math.h>

#define NH   8
#define HD   32
#define NP   4
#define EMB  256
#define IMG_H 100
#define IMG_W 100
#define NQ   10000
#define NV   10000
#define BS   4

#define W4S 36   // padded stride for 32-wide f32 rows
#define QPW 5    // queries per wave (persistent loop)
#define QPB (QPW * 4)          // 20 queries per block
#define NBLK (NQ / QPB)        // 500 blocks per batch

#define FENCE() asm volatile("" ::: "memory")

typedef __attribute__((ext_vector_type(8))) short bf16x8;
typedef __attribute__((ext_vector_type(4))) float f32x4;

// ---- ws layout ----------------------------------------------------------------------
#define KT_OFF    0                                   // kt  [BS][NP][NH][HD] f32 16 KB
#define KB_OFF    16384                               // kb                    512 B
#define BO2_OFF   17408                               // bo2 [EMB]             1 KB
#define WCF_OFF   18432                               // Wcomb f32 [EMB][EMB]  256 KB
#define WCB_OFF   (18432 + 262144)                    // Wcomb bf16            128 KB
#define PREB_OFF  (18432 + 262144 + 131072)           // pre bf16 [BS*NQ][EMB] 20.48 MB
#define WS_FULL   ((size_t)PREB_OFF + (size_t)BS * NQ * EMB * 2)

// ---------------- kprep: merged k1 (sampled keys -> kt,kb) + kcomb (Wcomb, bo2) ------
__global__ __launch_bounds__(256) void kprep(
    const float* __restrict__ query, const float* __restrict__ key,
    const float* __restrict__ refp,  const float* __restrict__ Woff,
    const float* __restrict__ boff,  const float* __restrict__ Wk,
    const float* __restrict__ bk,    const float* __restrict__ Wq,
    const float* __restrict__ bq,
    const float* __restrict__ Wo, const float* __restrict__ Wv,
    const float* __restrict__ bv, const float* __restrict__ bo,
    float* __restrict__ kt, float* __restrict__ kb,
    float* __restrict__ wcf, __hip_bfloat16* __restrict__ wcb,
    float* __restrict__ bo2)
{
    if (blockIdx.x < EMB) {
        __shared__ float sWv[HD * HD];
        __shared__ float sWoR[EMB];
        __shared__ float sws[4];
        int e = blockIdx.x, col = threadIdx.x;
        *(float4*)&sWv[col * 4] = *(const float4*)(Wv + col * 4);
        sWoR[col] = Wo[(size_t)e * EMB + col];
        __syncthreads();

        int d = col & 31;
        float s = 0.f;
        #pragma unroll
        for (int dd = 0; dd < HD; ++dd) s += sWoR[(col >> 5) * HD + dd] * sWv[dd * HD + d];
        wcf[(size_t)e * EMB + col] = s;
        if (wcb) wcb[(size_t)e * EMB + col] = __float2bfloat16(s);

        float pb = bv[d] * sWoR[col];
        #pragma unroll
        for (int o = 1; o < 64; o <<= 1) pb += __shfl_xor(pb, o);
        if ((col & 63) == 0) sws[col >> 6] = pb;
        __syncthreads();
        if (col == 0) bo2[e] = bo[e] + sws[0] + sws[1] + sws[2] + sws[3];
    } else {
        int bh = blockIdx.x - EMB;
        int b = bh >> 3, h = bh & 7;
        __shared__ float q0[HD];
        __shared__ float off[8];
        __shared__ float ks[NP][HD];
        __shared__ float kkl[NP][HD];
        int l = threadIdx.x;

        if (l < HD) q0[l] = query[(size_t)(b * NQ) * EMB + h * HD + l];
        __syncthreads();

        if (l < 8) {
            float s = boff[l];
            #pragma unroll
            for (int d = 0; d < HD; ++d) s += q0[d] * Woff[l * HD + d];
            off[l] = s;
        }
        __syncthreads();

        if (l < HD) {
            float refx = refp[(size_t)(b * NQ) * 2 + 0];
            float refy = refp[(size_t)(b * NQ) * 2 + 1];
            for (int p = 0; p < NP; ++p) {
                float x = refx * IMG_W + off[p * 2 + 0] - 0.5f;
                float y = refy * IMG_H + off[p * 2 + 1] - 0.5f;
                float x0f = floorf(x), y0f = floorf(y);
                int ix0 = (int)x0f, iy0 = (int)y0f;
                float fx = x - x0f, fy = y - y0f;
                float acc = 0.f;
                #pragma unroll
                for (int cy = 0; cy < 2; ++cy)
                    #pragma unroll
                    for (int cx = 0; cx < 2; ++cx) {
                        int xi = ix0 + cx, yi = iy0 + cy;
                        if ((unsigned)xi < IMG_W && (unsigned)yi < IMG_H) {
                            float wgt = (cx ? fx : 1.f - fx) * (cy ? fy : 1.f - fy);
                            acc += wgt * key[((size_t)b * NV + yi * IMG_W + xi) * EMB + h * HD + l];
                        }
                    }
                ks[p][l] = acc;
            }
        }
        __syncthreads();

        if (l < 128) {
            int p = l >> 5, dout = l & 31;
            float s = bk[dout];
            #pragma unroll
            for (int d = 0; d < HD; ++d) s += Wk[dout * HD + d] * ks[p][d];
            kkl[p][dout] = s;
        }
        __syncthreads();

        if (l < 128) {
            int p = l >> 5, d = l & 31;
            float s = 0.f;
            #pragma unroll
            for (int dd = 0; dd < HD; ++dd) s += Wq[dd * HD + d] * kkl[p][dd];
            kt[((b * NP + p) * NH + h) * HD + d] = s;
        }
        if (l < NP) {
            float s = 0.f;
            #pragma unroll
            for (int dd = 0; dd < HD; ++dd) s += bq[dd] * kkl[l][dd];
            kb[(b * NP + l) * NH + h] = s;
        }
    }
}

// ---------------- Kernel 2: persistent blocks — stage weights once, 20 queries -------
// Block = 4 waves; wave w owns QPW consecutive queries, looped. One __syncthreads
// total (weight staging); inside the loop everything is wave-local (FENCE only).
template<int BF16OUT>
__global__ __launch_bounds__(256) void k2_main(
    const float* __restrict__ query, const float* __restrict__ value,
    const float* __restrict__ refp,
    const float* __restrict__ Woff, const float* __restrict__ boff,
    const float* __restrict__ kt, const float* __restrict__ kb,
    float* __restrict__ pre, __hip_bfloat16* __restrict__ preb)
{
    __shared__ float sWoff[8 * W4S];
    __shared__ float sboff[8];
    __shared__ float skt[NP * NH * W4S];
    __shared__ float skb[NP * NH];
    __shared__ float qld[4][NH * W4S];
    __shared__ float offs[4][64];
    __shared__ float attnw[4][32];
    __shared__ int   soff4[4][32][4];
    __shared__ float swgt4[4][32][4];

    int tid = threadIdx.x;
    int qbase = blockIdx.x * QPB;            // 20 | NQ -> block stays in one batch
    int b = qbase / NQ;

    for (int i = tid; i < 8 * HD; i += 256) sWoff[(i >> 5) * W4S + (i & 31)] = Woff[i];
    if (tid < 8)  sboff[tid] = boff[tid];
    {
        int j = tid * 4;
        *(float4*)&skt[(j >> 5) * W4S + (j & 31)] =
            *(const float4*)(kt + b * (NP * NH * HD) + j);
    }
    if (tid < NP * NH) skb[tid] = kb[b * (NP * NH) + tid];

    int w = tid >> 6, lane = tid & 63;
    int h = lane >> 3, t = lane & 7;
    __syncthreads();   // weights ready; no further block-wide barriers

    #pragma unroll 1
    for (int it = 0; it < QPW; ++it) {
        int gq = qbase + w * QPW + it;

        // q row -> LDS (float4 by all 64 lanes), wave-local
        float4 qv = *(const float4*)(query + (size_t)gq * EMB + lane * 4);
        { int e = lane * 4; *(float4*)&qld[w][(e >> 5) * W4S + (e & 31)] = qv; }
        float refx = refp[(size_t)gq * 2 + 0];
        float refy = refp[(size_t)gq * 2 + 1];
        FENCE();   // same-wave DS write->read, in-order

        // register-cache q[h,:]
        float qr[HD];
        #pragma unroll
        for (int d = 0; d < HD; d += 4) {
            float4 v4 = *(const float4*)&qld[w][h * W4S + d];
            qr[d] = v4.x; qr[d + 1] = v4.y; qr[d + 2] = v4.z; qr[d + 3] = v4.w;
        }

        // sampling offsets: lane (h, j=t)
        {
            float s = sboff[t];
            const float* wr = &sWoff[t * W4S];
            #pragma unroll
            for (int d = 0; d < HD; d += 4) {
                float4 ww = *(const float4*)(wr + d);
                s += qr[d]*ww.x + qr[d+1]*ww.y + qr[d+2]*ww.z + qr[d+3]*ww.w;
            }
            offs[w][h * 8 + t] = s;
        }

        // logits via folded keys: plog[p] = q . kt[p,h,:] + kb[p,h]
        float plog[NP];
        #pragma unroll
        for (int p = 0; p < NP; ++p) {
            const float* kr = &skt[(p * NH + h) * W4S];
            float s = 0.f;
            #pragma unroll
            for (int k = 0; k < 4; ++k) s += qr[t + 8 * k] * kr[t + 8 * k];
            plog[p] = s;
        }
        #pragma unroll
        for (int p = 0; p < NP; ++p) {
            plog[p] += __shfl_xor(plog[p], 1, 8);
            plog[p] += __shfl_xor(plog[p], 2, 8);
            plog[p] += __shfl_xor(plog[p], 4, 8);
            plog[p] += skb[p * NH + h];
        }
        {
            float mm = fmaxf(fmaxf(plog[0], plog[1]), fmaxf(plog[2], plog[3]));
            float e0 = __expf(plog[0]-mm), e1 = __expf(plog[1]-mm);
            float e2 = __expf(plog[2]-mm), e3 = __expf(plog[3]-mm);
            float inv = 1.f / (e0 + e1 + e2 + e3);
            if (t < 4) {
                float a = (t == 0) ? e0 : (t == 1) ? e1 : (t == 2) ? e2 : e3;
                attnw[w][h * 4 + t] = a * inv;
            }
        }
        FENCE();

        // metadata: one (h2,p) per lane<32 — premultiplied weights + byte offsets
        if (lane < 32) {
            int h2 = lane >> 2, p = lane & 3;
            float x = refx * IMG_W + offs[w][h2 * 8 + p * 2 + 0] - 0.5f;
            float y = refy * IMG_H + offs[w][h2 * 8 + p * 2 + 1] - 0.5f;
            float x0f = floorf(x), y0f = floorf(y);
            int ix0 = (int)x0f, iy0 = (int)y0f;
            float fx = x - x0f, fy = y - y0f;
            float aw = attnw[w][lane];
            float wx1 = fx * aw, wx0 = aw - wx1;
            int bbase = b * (NV * EMB) + h2 * HD;
            int   o4[4]; float g4[4];
            #pragma unroll
            for (int c = 0; c < 4; ++c) {
                int cx = c & 1, cy = c >> 1;
                int xi = ix0 + cx, yi = iy0 + cy;
                bool valid = ((unsigned)xi < IMG_W) & ((unsigned)yi < IMG_H);
                int xc = min(max(xi, 0), IMG_W - 1);
                int yc = min(max(yi, 0), IMG_H - 1);
                o4[c] = (bbase + (yc * IMG_W + xc) * EMB) * 4;   // bytes
                float wv = (cx ? wx1 : wx0) * (cy ? fy : 1.f - fy);
                g4[c] = valid ? wv : 0.f;
            }
            int4   ov = {o4[0], o4[1], o4[2], o4[3]};
            float4 gv = {g4[0], g4[1], g4[2], g4[3]};
            *(int4*)&soff4[w][lane][0]   = ov;
            *(float4*)&swgt4[w][lane][0] = gv;
        }
        FENCE();

        // gather: lane = (head h, channel-group t); 16 float4 loads, 64 FMA
        {
            unsigned co = t * 16;
            const char* vb = (const char*)value;
            float4 acc = {0.f, 0.f, 0.f, 0.f};
            #pragma unroll
            for (int p = 0; p < NP; ++p) {
                int hp = h * 4 + p;
                int4   o4 = *(const int4*)&soff4[w][hp][0];
                float4 g4 = *(const float4*)&swgt4[w][hp][0];
                float4 v0 = *(const float4*)(vb + (unsigned)o4.x + co);
                float4 v1 = *(const float4*)(vb + (unsigned)o4.y + co);
                float4 v2 = *(const float4*)(vb + (unsigned)o4.z + co);
                float4 v3 = *(const float4*)(vb + (unsigned)o4.w + co);
                acc.x += g4.x*v0.x + g4.y*v1.x + g4.z*v2.x + g4.w*v3.x;
                acc.y += g4.x*v0.y + g4.y*v1.y + g4.z*v2.y + g4.w*v3.y;
                acc.z += g4.x*v0.z + g4.y*v1.z + g4.z*v2.z + g4.w*v3.z;
                acc.w += g4.x*v0.w + g4.y*v1.w + g4.z*v2.w + g4.w*v3.w;
            }
            int cb = t * 4;
            if (BF16OUT) {
                __hip_bfloat16 pk[4];
                pk[0] = __float2bfloat16(acc.x);
                pk[1] = __float2bfloat16(acc.y);
                pk[2] = __float2bfloat16(acc.z);
                pk[3] = __float2bfloat16(acc.w);
                *(ushort4*)((unsigned short*)preb + (size_t)gq * EMB + h * HD + cb) =
                    *(const ushort4*)&pk[0];
            } else {
                *(float4*)(pre + (size_t)gq * EMB + h * HD + cb) = acc;
            }
        }
        FENCE();   // soff4/swgt4 reuse next iteration is same-wave ordered
    }
}

// ---------------- Kernel 3a: MFMA bf16 GEMM, 32-row blocks (tail-balanced) -----------
__global__ __launch_bounds__(256) void k3_mfma(
    const __hip_bfloat16* __restrict__ preb, const __hip_bfloat16* __restrict__ wcb,
    float* __restrict__ outp, const float* __restrict__ query,
    const float* __restrict__ bo2)
{
    int w = threadIdx.x >> 6, lane = threadIdx.x & 63;
    size_t m0 = (size_t)blockIdx.x * 32;
    int n0 = w * 64;
    int lr = lane & 15, lg = lane >> 4;

    const short* pa = (const short*)preb;
    const short* pb = (const short*)wcb;

    f32x4 acc[2][4];
    #pragma unroll
    for (int mt = 0; mt < 2; ++mt)
        #pragma unroll
        for (int nt = 0; nt < 4; ++nt) acc[mt][nt] = (f32x4){0.f, 0.f, 0.f, 0.f};

    #pragma unroll
    for (int k0 = 0; k0 < EMB; k0 += 32) {
        bf16x8 af[2], bf[4];
        #pragma unroll
        for (int mt = 0; mt < 2; ++mt)
            af[mt] = *(const bf16x8*)(pa + (m0 + mt * 16 + lr) * EMB + k0 + lg * 8);
        #pragma unroll
        for (int nt = 0; nt < 4; ++nt)
            bf[nt] = *(const bf16x8*)(pb + (size_t)(n0 + nt * 16 + lr) * EMB + k0 + lg * 8);
        #pragma unroll
        for (int mt = 0; mt < 2; ++mt)
            #pragma unroll
            for (int nt = 0; nt < 4; ++nt)
                acc[mt][nt] = __builtin_amdgcn_mfma_f32_16x16x32_bf16(
                    af[mt], bf[nt], acc[mt][nt], 0, 0, 0);
    }

    float bov[4];
    #pragma unroll
    for (int nt = 0; nt < 4; ++nt) bov[nt] = bo2[n0 + nt * 16 + lr];

    #pragma unroll
    for (int mt = 0; mt < 2; ++mt)
        #pragma unroll
        for (int q = 0; q < 4; ++q) {
            size_t row = m0 + mt * 16 + lg * 4 + q;
            const float* qrow = query + row * EMB;
            float* orow = outp + row * EMB;
            #pragma unroll
            for (int nt = 0; nt < 4; ++nt) {
                int col = n0 + nt * 16 + lr;
                orow[col] = acc[mt][nt][q] + bov[nt] + qrow[col];
            }
        }
}

// ---------------- Kernel 3b: f32 fallback (in-place over d_out, Wcomb f32) -----------
__global__ __launch_bounds__(256) void k3_gemm(
    const float* __restrict__ pre, float* __restrict__ outp,
    const float* __restrict__ query, const float* __restrict__ wcf,
    const float* __restrict__ bo2)
{
    __shared__ float As[64 * EMB];
    int tid = threadIdx.x;
    size_t r0 = (size_t)blockIdx.x * 64;
    {
        const float4* src = (const float4*)(pre + r0 * EMB);
        float4* dst = (float4*)As;
        for (int i = tid; i < 64 * EMB / 4; i += 256) dst[i] = src[i];
    }
    __syncthreads();

    int w = tid >> 6, lane = tid & 63;
    int rb = w * 16;
    float acc[16][4];
    #pragma unroll
    for (int r = 0; r < 16; ++r)
        #pragma unroll
        for (int j = 0; j < 4; ++j) acc[r][j] = 0.f;

    for (int kc = 0; kc < EMB / 4; ++kc) {
        float4 wreg[4];
        #pragma unroll
        for (int j = 0; j < 4; ++j)
            wreg[j] = *(const float4*)&wcf[(size_t)(lane + 64 * j) * EMB + kc * 4];
        #pragma unroll
        for (int r = 0; r < 16; ++r) {
            float4 a = *(const float4*)&As[(rb + r) * EMB + kc * 4];
            #pragma unroll
            for (int j = 0; j < 4; ++j)
                acc[r][j] += a.x * wreg[j].x + a.y * wreg[j].y
                           + a.z * wreg[j].z + a.w * wreg[j].w;
        }
    }

    #pragma unroll
    for (int r = 0; r < 16; ++r) {
        size_t row = r0 + rb + r;
        #pragma unroll
        for (int j = 0; j < 4; ++j) {
            int c = lane + 64 * j;
            outp[row * EMB + c] = acc[r][j] + bo2[c] + query[row * EMB + c];
        }
    }
}

extern "C" void kernel_launch(void* const* d_in, const int* in_sizes, int n_in,
                              void* d_out, int out_size, void* d_ws, size_t ws_size,
                              hipStream_t stream) {
    const float* query = (const float*)d_in[0];
    const float* key   = (const float*)d_in[1];
    const float* value = (const float*)d_in[2];
    const float* refp  = (const float*)d_in[3];
    const float* Wq   = (const float*)d_in[4];
    const float* bq   = (const float*)d_in[5];
    const float* Wk   = (const float*)d_in[6];
    const float* bk   = (const float*)d_in[7];
    const float* Wv   = (const float*)d_in[8];
    const float* bv   = (const float*)d_in[9];
    const float* Woff = (const float*)d_in[10];
    const float* boff = (const float*)d_in[11];
    const float* Wo   = (const float*)d_in[12];
    const float* bo   = (const float*)d_in[13];
    (void)in_sizes; (void)n_in; (void)out_size;

    float* out = (float*)d_out;
    char*  ws  = (char*)d_ws;
    float* kt  = (float*)(ws + KT_OFF);
    float* kb  = (float*)(ws + KB_OFF);
    float* bo2 = (float*)(ws + BO2_OFF);
    float* wcf = (float*)(ws + WCF_OFF);
    __hip_bfloat16* wcb = (__hip_bfloat16*)(ws + WCB_OFF);

    bool full = (ws_size >= WS_FULL);

    kprep<<<EMB + BS * NH, 256, 0, stream>>>(query, key, refp, Woff, boff, Wk, bk,
                                             Wq, bq, Wo, Wv, bv, bo,
                                             kt, kb, wcf, full ? wcb : nullptr, bo2);

    if (full) {
        __hip_bfloat16* preb = (__hip_bfloat16*)(ws + PREB_OFF);
        k2_main<1><<<BS * NBLK, 256, 0, stream>>>(query, value, refp, Woff, boff,
                                                  kt, kb, nullptr, preb);
        k3_mfma<<<BS * NQ / 32, 256, 0, stream>>>(preb, wcb, out, query, bo2);
    } else {
        k2_main<0><<<BS * NBLK, 256, 0, stream>>>(query, value, refp, Woff, boff,
                                                  kt, kb, out, nullptr);
        k3_gemm<<<BS * NQ / 64, 256, 0, stream>>>(out, out, query, wcf, bo2);
    }
}

// Round 17
// 83.680 us; speedup vs baseline: 1.0492x; 1.0492x over previous
//
#include <hip/hip_runtime.h>
#include <hip/hip_bf16.h>
#include <math.h>

#define NH   8
#define HD   32
#define NP   4
#define EMB  256
#define IMG_H 100
#define IMG_W 100
#define NQ   10000
#define NV   10000
#define BS   4

#define W4S 36   // padded stride for 32-wide f32 rows

#define FENCE() asm volatile("" ::: "memory")

typedef __attribute__((ext_vector_type(8))) short bf16x8;
typedef __attribute__((ext_vector_type(4))) float f32x4;

// ---- ws layout ----------------------------------------------------------------------
#define KT_OFF    0                                   // kt  [BS][NP][NH][HD] f32 16 KB
#define KB_OFF    16384                               // kb                    512 B
#define BO2_OFF   17408                               // bo2 [EMB]             1 KB
#define WCF_OFF   18432                               // Wcomb f32 [EMB][EMB]  256 KB
#define WCB_OFF   (18432 + 262144)                    // Wcomb bf16            128 KB
#define PREB_OFF  (18432 + 262144 + 131072)           // pre bf16 [BS*NQ][EMB] 20.48 MB
#define WS_FULL   ((size_t)PREB_OFF + (size_t)BS * NQ * EMB * 2)

// ---------------- kprep: merged k1 (sampled keys -> kt,kb) + kcomb (Wcomb, bo2) ------
__global__ __launch_bounds__(256) void kprep(
    const float* __restrict__ query, const float* __restrict__ key,
    const float* __restrict__ refp,  const float* __restrict__ Woff,
    const float* __restrict__ boff,  const float* __restrict__ Wk,
    const float* __restrict__ bk,    const float* __restrict__ Wq,
    const float* __restrict__ bq,
    const float* __restrict__ Wo, const float* __restrict__ Wv,
    const float* __restrict__ bv, const float* __restrict__ bo,
    float* __restrict__ kt, float* __restrict__ kb,
    float* __restrict__ wcf, __hip_bfloat16* __restrict__ wcb,
    float* __restrict__ bo2)
{
    if (blockIdx.x < EMB) {
        __shared__ float sWv[HD * HD];
        __shared__ float sWoR[EMB];
        __shared__ float sws[4];
        int e = blockIdx.x, col = threadIdx.x;
        *(float4*)&sWv[col * 4] = *(const float4*)(Wv + col * 4);
        sWoR[col] = Wo[(size_t)e * EMB + col];
        __syncthreads();

        int d = col & 31;
        float s = 0.f;
        #pragma unroll
        for (int dd = 0; dd < HD; ++dd) s += sWoR[(col >> 5) * HD + dd] * sWv[dd * HD + d];
        wcf[(size_t)e * EMB + col] = s;
        if (wcb) wcb[(size_t)e * EMB + col] = __float2bfloat16(s);

        float pb = bv[d] * sWoR[col];
        #pragma unroll
        for (int o = 1; o < 64; o <<= 1) pb += __shfl_xor(pb, o);
        if ((col & 63) == 0) sws[col >> 6] = pb;
        __syncthreads();
        if (col == 0) bo2[e] = bo[e] + sws[0] + sws[1] + sws[2] + sws[3];
    } else {
        int bh = blockIdx.x - EMB;
        int b = bh >> 3, h = bh & 7;
        __shared__ float q0[HD];
        __shared__ float off[8];
        __shared__ float ks[NP][HD];
        __shared__ float kkl[NP][HD];
        int l = threadIdx.x;

        if (l < HD) q0[l] = query[(size_t)(b * NQ) * EMB + h * HD + l];
        __syncthreads();

        if (l < 8) {
            float s = boff[l];
            #pragma unroll
            for (int d = 0; d < HD; ++d) s += q0[d] * Woff[l * HD + d];
            off[l] = s;
        }
        __syncthreads();

        if (l < HD) {
            float refx = refp[(size_t)(b * NQ) * 2 + 0];
            float refy = refp[(size_t)(b * NQ) * 2 + 1];
            for (int p = 0; p < NP; ++p) {
                float x = refx * IMG_W + off[p * 2 + 0] - 0.5f;
                float y = refy * IMG_H + off[p * 2 + 1] - 0.5f;
                float x0f = floorf(x), y0f = floorf(y);
                int ix0 = (int)x0f, iy0 = (int)y0f;
                float fx = x - x0f, fy = y - y0f;
                float acc = 0.f;
                #pragma unroll
                for (int cy = 0; cy < 2; ++cy)
                    #pragma unroll
                    for (int cx = 0; cx < 2; ++cx) {
                        int xi = ix0 + cx, yi = iy0 + cy;
                        if ((unsigned)xi < IMG_W && (unsigned)yi < IMG_H) {
                            float wgt = (cx ? fx : 1.f - fx) * (cy ? fy : 1.f - fy);
                            acc += wgt * key[((size_t)b * NV + yi * IMG_W + xi) * EMB + h * HD + l];
                        }
                    }
                ks[p][l] = acc;
            }
        }
        __syncthreads();

        if (l < 128) {
            int p = l >> 5, dout = l & 31;
            float s = bk[dout];
            #pragma unroll
            for (int d = 0; d < HD; ++d) s += Wk[dout * HD + d] * ks[p][d];
            kkl[p][dout] = s;
        }
        __syncthreads();

        if (l < 128) {
            int p = l >> 5, d = l & 31;
            float s = 0.f;
            #pragma unroll
            for (int dd = 0; dd < HD; ++dd) s += Wq[dd * HD + d] * kkl[p][dd];
            kt[((b * NP + p) * NH + h) * HD + d] = s;
        }
        if (l < NP) {
            float s = 0.f;
            #pragma unroll
            for (int dd = 0; dd < HD; ++dd) s += bq[dd] * kkl[l][dd];
            kb[(b * NP + l) * NH + h] = s;
        }
    }
}

// ---------------- Kernel 2 (r13-exact): per-query pipeline, scalar-FMA gather --------
template<int BF16OUT>
__global__ __launch_bounds__(256) void k2_main(
    const float* __restrict__ query, const float* __restrict__ value,
    const float* __restrict__ refp,
    const float* __restrict__ Woff, const float* __restrict__ boff,
    const float* __restrict__ kt, const float* __restrict__ kb,
    float* __restrict__ pre, __hip_bfloat16* __restrict__ preb)
{
    __shared__ float sWoff[8 * W4S];
    __shared__ float sboff[8];
    __shared__ float skt[NP * NH * W4S];
    __shared__ float skb[NP * NH];
    __shared__ float qld[4][NH * W4S];
    __shared__ float offs[4][64];
    __shared__ float attnw[4][32];
    __shared__ int   soff4[4][32][4];
    __shared__ float swgt4[4][32][4];

    int tid = threadIdx.x;
    int b0 = (blockIdx.x * 4) / NQ;          // uniform across block (4 | NQ)

    for (int i = tid; i < 8 * HD; i += 256) sWoff[(i >> 5) * W4S + (i & 31)] = Woff[i];
    if (tid < 8)  sboff[tid] = boff[tid];
    {
        int j = tid * 4;
        *(float4*)&skt[(j >> 5) * W4S + (j & 31)] =
            *(const float4*)(kt + b0 * (NP * NH * HD) + j);
    }
    if (tid < NP * NH) skb[tid] = kb[b0 * (NP * NH) + tid];

    int w = tid >> 6, lane = tid & 63;
    int gq = blockIdx.x * 4 + w;
    int b = b0;

    float4 qv = *(const float4*)(query + (size_t)gq * EMB + lane * 4);
    { int e = lane * 4; *(float4*)&qld[w][(e >> 5) * W4S + (e & 31)] = qv; }
    float refx = refp[(size_t)gq * 2 + 0];
    float refy = refp[(size_t)gq * 2 + 1];
    __syncthreads();

    int h = lane >> 3, t = lane & 7;

    // register-cache q[h,:]
    float qr[HD];
    #pragma unroll
    for (int d = 0; d < HD; d += 4) {
        float4 v4 = *(const float4*)&qld[w][h * W4S + d];
        qr[d] = v4.x; qr[d + 1] = v4.y; qr[d + 2] = v4.z; qr[d + 3] = v4.w;
    }

    // sampling offsets: lane (h, j=t)
    {
        float s = sboff[t];
        const float* wr = &sWoff[t * W4S];
        #pragma unroll
        for (int d = 0; d < HD; d += 4) {
            float4 ww = *(const float4*)(wr + d);
            s += qr[d]*ww.x + qr[d+1]*ww.y + qr[d+2]*ww.z + qr[d+3]*ww.w;
        }
        offs[w][h * 8 + t] = s;
    }

    // logits via folded keys: plog[p] = q . kt[p,h,:] + kb[p,h]
    float plog[NP];
    #pragma unroll
    for (int p = 0; p < NP; ++p) {
        const float* kr = &skt[(p * NH + h) * W4S];
        float s = 0.f;
        #pragma unroll
        for (int k = 0; k < 4; ++k) s += qr[t + 8 * k] * kr[t + 8 * k];
        plog[p] = s;
    }
    #pragma unroll
    for (int p = 0; p < NP; ++p) {
        plog[p] += __shfl_xor(plog[p], 1, 8);
        plog[p] += __shfl_xor(plog[p], 2, 8);
        plog[p] += __shfl_xor(plog[p], 4, 8);
        plog[p] += skb[p * NH + h];
    }
    {
        float mm = fmaxf(fmaxf(plog[0], plog[1]), fmaxf(plog[2], plog[3]));
        float e0 = __expf(plog[0]-mm), e1 = __expf(plog[1]-mm);
        float e2 = __expf(plog[2]-mm), e3 = __expf(plog[3]-mm);
        float inv = 1.f / (e0 + e1 + e2 + e3);
        if (t < 4) {
            float a = (t == 0) ? e0 : (t == 1) ? e1 : (t == 2) ? e2 : e3;
            attnw[w][h * 4 + t] = a * inv;
        }
    }
    FENCE();

    // metadata: one (h2,p) per lane<32 — premultiplied weights + byte offsets
    if (lane < 32) {
        int h2 = lane >> 2, p = lane & 3;
        float x = refx * IMG_W + offs[w][h2 * 8 + p * 2 + 0] - 0.5f;
        float y = refy * IMG_H + offs[w][h2 * 8 + p * 2 + 1] - 0.5f;
        float x0f = floorf(x), y0f = floorf(y);
        int ix0 = (int)x0f, iy0 = (int)y0f;
        float fx = x - x0f, fy = y - y0f;
        float aw = attnw[w][lane];
        float wx1 = fx * aw, wx0 = aw - wx1;
        int bbase = b * (NV * EMB) + h2 * HD;
        int   o4[4]; float g4[4];
        #pragma unroll
        for (int c = 0; c < 4; ++c) {
            int cx = c & 1, cy = c >> 1;
            int xi = ix0 + cx, yi = iy0 + cy;
            bool valid = ((unsigned)xi < IMG_W) & ((unsigned)yi < IMG_H);
            int xc = min(max(xi, 0), IMG_W - 1);
            int yc = min(max(yi, 0), IMG_H - 1);
            o4[c] = (bbase + (yc * IMG_W + xc) * EMB) * 4;   // bytes
            float wv = (cx ? wx1 : wx0) * (cy ? fy : 1.f - fy);
            g4[c] = valid ? wv : 0.f;
        }
        int4   ov = {o4[0], o4[1], o4[2], o4[3]};
        float4 gv = {g4[0], g4[1], g4[2], g4[3]};
        *(int4*)&soff4[w][lane][0]   = ov;
        *(float4*)&swgt4[w][lane][0] = gv;
    }
    FENCE();

    // gather: lane = (head h, channel-group t); 16 float4 loads, 64 FMA
    {
        unsigned co = t * 16;
        const char* vb = (const char*)value;
        float4 acc = {0.f, 0.f, 0.f, 0.f};
        #pragma unroll
        for (int p = 0; p < NP; ++p) {
            int hp = h * 4 + p;
            int4   o4 = *(const int4*)&soff4[w][hp][0];
            float4 g4 = *(const float4*)&swgt4[w][hp][0];
            float4 v0 = *(const float4*)(vb + (unsigned)o4.x + co);
            float4 v1 = *(const float4*)(vb + (unsigned)o4.y + co);
            float4 v2 = *(const float4*)(vb + (unsigned)o4.z + co);
            float4 v3 = *(const float4*)(vb + (unsigned)o4.w + co);
            acc.x += g4.x*v0.x + g4.y*v1.x + g4.z*v2.x + g4.w*v3.x;
            acc.y += g4.x*v0.y + g4.y*v1.y + g4.z*v2.y + g4.w*v3.y;
            acc.z += g4.x*v0.z + g4.y*v1.z + g4.z*v2.z + g4.w*v3.z;
            acc.w += g4.x*v0.w + g4.y*v1.w + g4.z*v2.w + g4.w*v3.w;
        }
        int cb = t * 4;
        if (BF16OUT) {
            __hip_bfloat16 pk[4];
            pk[0] = __float2bfloat16(acc.x);
            pk[1] = __float2bfloat16(acc.y);
            pk[2] = __float2bfloat16(acc.z);
            pk[3] = __float2bfloat16(acc.w);
            *(ushort4*)((unsigned short*)preb + (size_t)gq * EMB + h * HD + cb) =
                *(const ushort4*)&pk[0];
        } else {
            *(float4*)(pre + (size_t)gq * EMB + h * HD + cb) = acc;
        }
    }
}

// ---------------- Kernel 3a: MFMA bf16 GEMM, 32-row blocks (tail-balanced) -----------
__global__ __launch_bounds__(256) void k3_mfma(
    const __hip_bfloat16* __restrict__ preb, const __hip_bfloat16* __restrict__ wcb,
    float* __restrict__ outp, const float* __restrict__ query,
    const float* __restrict__ bo2)
{
    int w = threadIdx.x >> 6, lane = threadIdx.x & 63;
    size_t m0 = (size_t)blockIdx.x * 32;
    int n0 = w * 64;
    int lr = lane & 15, lg = lane >> 4;

    const short* pa = (const short*)preb;
    const short* pb = (const short*)wcb;

    f32x4 acc[2][4];
    #pragma unroll
    for (int mt = 0; mt < 2; ++mt)
        #pragma unroll
        for (int nt = 0; nt < 4; ++nt) acc[mt][nt] = (f32x4){0.f, 0.f, 0.f, 0.f};

    #pragma unroll
    for (int k0 = 0; k0 < EMB; k0 += 32) {
        bf16x8 af[2], bf[4];
        #pragma unroll
        for (int mt = 0; mt < 2; ++mt)
            af[mt] = *(const bf16x8*)(pa + (m0 + mt * 16 + lr) * EMB + k0 + lg * 8);
        #pragma unroll
        for (int nt = 0; nt < 4; ++nt)
            bf[nt] = *(const bf16x8*)(pb + (size_t)(n0 + nt * 16 + lr) * EMB + k0 + lg * 8);
        #pragma unroll
        for (int mt = 0; mt < 2; ++mt)
            #pragma unroll
            for (int nt = 0; nt < 4; ++nt)
                acc[mt][nt] = __builtin_amdgcn_mfma_f32_16x16x32_bf16(
                    af[mt], bf[nt], acc[mt][nt], 0, 0, 0);
    }

    float bov[4];
    #pragma unroll
    for (int nt = 0; nt < 4; ++nt) bov[nt] = bo2[n0 + nt * 16 + lr];

    #pragma unroll
    for (int mt = 0; mt < 2; ++mt)
        #pragma unroll
        for (int q = 0; q < 4; ++q) {
            size_t row = m0 + mt * 16 + lg * 4 + q;
            const float* qrow = query + row * EMB;
            float* orow = outp + row * EMB;
            #pragma unroll
            for (int nt = 0; nt < 4; ++nt) {
                int col = n0 + nt * 16 + lr;
                orow[col] = acc[mt][nt][q] + bov[nt] + qrow[col];
            }
        }
}

// ---------------- Kernel 3b: f32 fallback (in-place over d_out, Wcomb f32) -----------
__global__ __launch_bounds__(256) void k3_gemm(
    const float* __restrict__ pre, float* __restrict__ outp,
    const float* __restrict__ query, const float* __restrict__ wcf,
    const float* __restrict__ bo2)
{
    __shared__ float As[64 * EMB];
    int tid = threadIdx.x;
    size_t r0 = (size_t)blockIdx.x * 64;
    {
        const float4* src = (const float4*)(pre + r0 * EMB);
        float4* dst = (float4*)As;
        for (int i = tid; i < 64 * EMB / 4; i += 256) dst[i] = src[i];
    }
    __syncthreads();

    int w = tid >> 6, lane = tid & 63;
    int rb = w * 16;
    float acc[16][4];
    #pragma unroll
    for (int r = 0; r < 16; ++r)
        #pragma unroll
        for (int j = 0; j < 4; ++j) acc[r][j] = 0.f;

    for (int kc = 0; kc < EMB / 4; ++kc) {
        float4 wreg[4];
        #pragma unroll
        for (int j = 0; j < 4; ++j)
            wreg[j] = *(const float4*)&wcf[(size_t)(lane + 64 * j) * EMB + kc * 4];
        #pragma unroll
        for (int r = 0; r < 16; ++r) {
            float4 a = *(const float4*)&As[(rb + r) * EMB + kc * 4];
            #pragma unroll
            for (int j = 0; j < 4; ++j)
                acc[r][j] += a.x * wreg[j].x + a.y * wreg[j].y
                           + a.z * wreg[j].z + a.w * wreg[j].w;
        }
    }

    #pragma unroll
    for (int r = 0; r < 16; ++r) {
        size_t row = r0 + rb + r;
        #pragma unroll
        for (int j = 0; j < 4; ++j) {
            int c = lane + 64 * j;
            outp[row * EMB + c] = acc[r][j] + bo2[c] + query[row * EMB + c];
        }
    }
}

extern "C" void kernel_launch(void* const* d_in, const int* in_sizes, int n_in,
                              void* d_out, int out_size, void* d_ws, size_t ws_size,
                              hipStream_t stream) {
    const float* query = (const float*)d_in[0];
    const float* key   = (const float*)d_in[1];
    const float* value = (const float*)d_in[2];
    const float* refp  = (const float*)d_in[3];
    const float* Wq   = (const float*)d_in[4];
    const float* bq   = (const float*)d_in[5];
    const float* Wk   = (const float*)d_in[6];
    const float* bk   = (const float*)d_in[7];
    const float* Wv   = (const float*)d_in[8];
    const float* bv   = (const float*)d_in[9];
    const float* Woff = (const float*)d_in[10];
    const float* boff = (const float*)d_in[11];
    const float* Wo   = (const float*)d_in[12];
    const float* bo   = (const float*)d_in[13];
    (void)in_sizes; (void)n_in; (void)out_size;

    float* out = (float*)d_out;
    char*  ws  = (char*)d_ws;
    float* kt  = (float*)(ws + KT_OFF);
    float* kb  = (float*)(ws + KB_OFF);
    float* bo2 = (float*)(ws + BO2_OFF);
    float* wcf = (float*)(ws + WCF_OFF);
    __hip_bfloat16* wcb = (__hip_bfloat16*)(ws + WCB_OFF);

    bool full = (ws_size >= WS_FULL);

    kprep<<<EMB + BS * NH, 256, 0, stream>>>(query, key, refp, Woff, boff, Wk, bk,
                                             Wq, bq, Wo, Wv, bv, bo,
                                             kt, kb, wcf, full ? wcb : nullptr, bo2);

    if (full) {
        __hip_bfloat16* preb = (__hip_bfloat16*)(ws + PREB_OFF);
        k2_main<1><<<BS * NQ / 4, 256, 0, stream>>>(query, value, refp, Woff, boff,
                                                    kt, kb, nullptr, preb);
        k3_mfma<<<BS * NQ / 32, 256, 0, stream>>>(preb, wcb, out, query, bo2);
    } else {
        k2_main<0><<<BS * NQ / 4, 256, 0, stream>>>(query, value, refp, Woff, boff,
                                                    kt, kb, out, nullptr);
        k3_gemm<<<BS * NQ / 64, 256, 0, stream>>>(out, out, query, wcf, bo2);
    }
}